// Round 2
// baseline (347.468 us; speedup 1.0000x reference)
//
#include <hip/hip_runtime.h>
#include <hip/hip_fp16.h>
#include <math.h>

// MaxSim contrastive loss, MI355X.
// Pass 1: inverse L2 norms (memory-bound).
// Pass 2: fused maxsim GEMM: raw fp32 -> LDS (global_load_lds, XOR-swizzled via
//         pre-swizzled source), cvt to fp16 fragments, mfma 16x16x32, epilogue
//         applies (1/|k|)*mask per column and reduces row-max -> partials.
// Pass 3: combine partials, apply 1/|q| and q_mask, logits -> softplus -> mean.

constexpr int NB = 128;
constexpr int LQ = 256;
constexpr int LK = 512;
constexpr int DD = 1024;

#define TEMP_INV 20.0f
#define EPSN 1e-12f

typedef __fp16 fp16x2 __attribute__((ext_vector_type(2)));   // cvt_pkrtz return type
typedef _Float16 f16x8 __attribute__((ext_vector_type(8)));  // MFMA operand type
typedef float f32x4 __attribute__((ext_vector_type(4)));

// ---------------- pass 1: inverse L2 norms ----------------
__global__ __launch_bounds__(256) void norms_kernel(
    const float* __restrict__ q, const float* __restrict__ pk,
    const float* __restrict__ nk, float* __restrict__ inv) {
  int row = blockIdx.x;
  const float* src;
  int r;
  if (row < NB * LQ) { src = q; r = row; }
  else if (row < NB * LQ + NB * LK) { src = pk; r = row - NB * LQ; }
  else { src = nk; r = row - NB * LQ - NB * LK; }
  const float4* p = reinterpret_cast<const float4*>(src + (size_t)r * DD);
  float4 v = p[threadIdx.x];
  float s = v.x * v.x + v.y * v.y + v.z * v.z + v.w * v.w;
  #pragma unroll
  for (int o = 32; o; o >>= 1) s += __shfl_down(s, o);
  __shared__ float red[4];
  int lane = threadIdx.x & 63, w = threadIdx.x >> 6;
  if (lane == 0) red[w] = s;
  __syncthreads();
  if (threadIdx.x == 0) {
    float t = red[0] + red[1] + red[2] + red[3];
    inv[row] = 1.0f / fmaxf(sqrtf(t), EPSN);
  }
}

// ---------------- pass 2: fused maxsim GEMM ----------------
#define BM 128
#define BN 128
#define BK 32

__device__ inline f16x8 cvt8(float4 a, float4 b) {
  union { f16x8 v; fp16x2 h[4]; } u;
  u.h[0] = __builtin_amdgcn_cvt_pkrtz(a.x, a.y);
  u.h[1] = __builtin_amdgcn_cvt_pkrtz(a.z, a.w);
  u.h[2] = __builtin_amdgcn_cvt_pkrtz(b.x, b.y);
  u.h[3] = __builtin_amdgcn_cvt_pkrtz(b.z, b.w);
  return u.v;
}

__device__ inline void gload16(const float* g, void* l) {
  __builtin_amdgcn_global_load_lds(
      (const __attribute__((address_space(1))) void*)g,
      (__attribute__((address_space(3))) void*)l, 16, 0, 0);
}

__global__ __launch_bounds__(256) void maxsim_kernel(
    const float* __restrict__ q, const float* __restrict__ pk,
    const float* __restrict__ nk, const int* __restrict__ pmask,
    const int* __restrict__ nmask, const float* __restrict__ inv,
    float* __restrict__ part) {
  __shared__ float As[BM * BK];   // 16 KB, XOR-swizzled storage
  __shared__ float Bs[BN * BK];   // 16 KB
  __shared__ float cs[BN];
  __shared__ float rmax[BM][2];

  const int x = blockIdx.x;
  const int b = blockIdx.y;
  const int mt = x >> 3;         // 0..1  (q tile)
  const int nt = (x >> 1) & 3;   // 0..3  (key tile)
  const int kt = x & 1;          // 0=pos 1=neg

  const float* kbase = kt ? nk : pk;
  const int* mbase = kt ? nmask : pmask;
  const float* invk = inv + NB * LQ + (size_t)kt * NB * LK;

  const float* Ag = q + ((size_t)b * LQ + mt * BM) * DD;
  const float* Bg = kbase + ((size_t)b * LK + nt * BN) * DD;

  const int tid = threadIdx.x;
  const int lane = tid & 63;
  const int w = tid >> 6;
  const int wr = w >> 1, wc = w & 1;

  // staging map: thread t -> LDS linear (row = t/8, group16B = t%8);
  // pre-swizzle the GLOBAL source group so a reader XORing with (row&7) gets
  // the logical group back (global_load_lds dest must stay linear).
  const int srow = tid >> 3;
  const int sgrp = tid & 7;
  const int gsrc = sgrp ^ (srow & 7);   // (srow+32i)&7 == srow&7

  const int frow = lane & 15;
  const int kgrp = lane >> 4;   // 0..3
  const int g0 = kgrp * 2;

  f32x4 acc[4][4] = {};

  for (int kk = 0; kk < DD / BK; ++kk) {
    const int koff = kk * BK;
    #pragma unroll
    for (int i = 0; i < 4; ++i)
      gload16(Ag + (size_t)(srow + 32 * i) * DD + koff + gsrc * 4,
              (char*)As + i * 4096 + w * 1024);
    #pragma unroll
    for (int i = 0; i < 4; ++i)
      gload16(Bg + (size_t)(srow + 32 * i) * DD + koff + gsrc * 4,
              (char*)Bs + i * 4096 + w * 1024);
    __syncthreads();

    f16x8 af[4], bf[4];
    #pragma unroll
    for (int m = 0; m < 4; ++m) {
      int row = wr * 64 + m * 16 + frow;
      int base = row * BK;
      int sw = row & 7;
      float4 x0 = *(const float4*)&As[base + ((g0 ^ sw) << 2)];
      float4 x1 = *(const float4*)&As[base + (((g0 + 1) ^ sw) << 2)];
      af[m] = cvt8(x0, x1);
    }
    #pragma unroll
    for (int n = 0; n < 4; ++n) {
      int row = wc * 64 + n * 16 + frow;
      int base = row * BK;
      int sw = row & 7;
      float4 x0 = *(const float4*)&Bs[base + ((g0 ^ sw) << 2)];
      float4 x1 = *(const float4*)&Bs[base + (((g0 + 1) ^ sw) << 2)];
      bf[n] = cvt8(x0, x1);
    }
    #pragma unroll
    for (int m = 0; m < 4; ++m)
      #pragma unroll
      for (int n = 0; n < 4; ++n)
        acc[m][n] = __builtin_amdgcn_mfma_f32_16x16x32_f16(af[m], bf[n], acc[m][n], 0, 0, 0);
    __syncthreads();
  }

  // column scales: (1/|k|) * mask  (masked keys contribute exactly 0, matching
  // the reference's multiplicative masking before the max)
  if (tid < BN) {
    int key = nt * BN + tid;
    cs[tid] = invk[(size_t)b * LK + key] * (mbase[(size_t)b * LK + key] ? 1.0f : 0.0f);
  }
  __syncthreads();

  // per-lane row-max over this wave's 4 column fragments
  float vmax[4][4];
  #pragma unroll
  for (int m = 0; m < 4; ++m)
    #pragma unroll
    for (int r = 0; r < 4; ++r) vmax[m][r] = -INFINITY;
  #pragma unroll
  for (int n = 0; n < 4; ++n) {
    float s = cs[wc * 64 + n * 16 + frow];
    #pragma unroll
    for (int m = 0; m < 4; ++m)
      #pragma unroll
      for (int r = 0; r < 4; ++r)
        vmax[m][r] = fmaxf(vmax[m][r], acc[m][n][r] * s);
  }
  // reduce across the 16 lanes sharing rows (lane&15 varies = columns)
  #pragma unroll
  for (int off = 1; off < 16; off <<= 1)
    #pragma unroll
    for (int m = 0; m < 4; ++m)
      #pragma unroll
      for (int r = 0; r < 4; ++r)
        vmax[m][r] = fmaxf(vmax[m][r], __shfl_xor(vmax[m][r], off));
  if ((lane & 15) == 0) {
    #pragma unroll
    for (int m = 0; m < 4; ++m)
      #pragma unroll
      for (int r = 0; r < 4; ++r)
        rmax[wr * 64 + m * 16 + kgrp * 4 + r][wc] = vmax[m][r];
  }
  __syncthreads();
  if (tid < BM) {
    float v = fmaxf(rmax[tid][0], rmax[tid][1]);
    part[(((size_t)kt * NB + b) * 4 + nt) * LQ + mt * BM + tid] = v;
  }
}

// ---------------- pass 3: logits + softplus per batch ----------------
__global__ __launch_bounds__(256) void logits_kernel(
    const float* __restrict__ part, const float* __restrict__ inv,
    const int* __restrict__ qmask, float* __restrict__ nll) {
  int b = blockIdx.x;
  int t = threadIdx.x;  // = lq
  float mp = -INFINITY, mn = -INFINITY;
  #pragma unroll
  for (int ntile = 0; ntile < 4; ++ntile) {
    mp = fmaxf(mp, part[(((size_t)0 * NB + b) * 4 + ntile) * LQ + t]);
    mn = fmaxf(mn, part[(((size_t)1 * NB + b) * 4 + ntile) * LQ + t]);
  }
  float iq = inv[(size_t)b * LQ + t];
  float qm = qmask[(size_t)b * LQ + t] ? 1.0f : 0.0f;
  float p = mp * iq * qm;
  float n = mn * iq * qm;
  #pragma unroll
  for (int o = 32; o; o >>= 1) { p += __shfl_down(p, o); n += __shfl_down(n, o); }
  __shared__ float sp[4], sn[4];
  int lane = t & 63, w = t >> 6;
  if (lane == 0) { sp[w] = p; sn[w] = n; }
  __syncthreads();
  if (t == 0) {
    float ps = sp[0] + sp[1] + sp[2] + sp[3];
    float ns = sn[0] + sn[1] + sn[2] + sn[3];
    float z = (ns - ps) * TEMP_INV;
    nll[b] = z > 0.0f ? z + log1pf(expf(-z)) : log1pf(expf(z));
  }
}

__global__ void finalize_kernel(const float* __restrict__ nll, float* __restrict__ out) {
  __shared__ float s[128];
  int t = threadIdx.x;
  s[t] = nll[t];
  __syncthreads();
  #pragma unroll
  for (int o = 64; o; o >>= 1) {
    if (t < o) s[t] += s[t + o];
    __syncthreads();
  }
  if (t == 0) out[0] = s[0] * (1.0f / 128.0f);
}

extern "C" void kernel_launch(void* const* d_in, const int* in_sizes, int n_in,
                              void* d_out, int out_size, void* d_ws, size_t ws_size,
                              hipStream_t stream) {
  const float* q = (const float*)d_in[0];
  const float* pk = (const float*)d_in[1];
  const float* nk = (const float*)d_in[2];
  const int* qm = (const int*)d_in[3];
  const int* pm = (const int*)d_in[4];
  const int* nm = (const int*)d_in[5];

  float* ws = (float*)d_ws;
  float* inv = ws;                 // 163840 floats: [invq | invk_pos | invk_neg]
  float* part = ws + 163840;       // 262144 floats: [kt][b][nt][lq] partial maxes
  float* nll = part + 262144;      // 128 floats

  norms_kernel<<<NB * LQ + 2 * NB * LK, 256, 0, stream>>>(q, pk, nk, inv);
  maxsim_kernel<<<dim3(16, NB, 1), 256, 0, stream>>>(q, pk, nk, pm, nm, inv, part);
  logits_kernel<<<NB, 256, 0, stream>>>(part, inv, qm, nll);
  finalize_kernel<<<1, 128, 0, stream>>>(nll, (float*)d_out);
}

// Round 3
// 274.708 us; speedup vs baseline: 1.2649x; 1.2649x over previous
//
#include <hip/hip_runtime.h>
#include <hip/hip_fp16.h>
#include <math.h>

// MaxSim contrastive loss, MI355X — fused single-pass version.
// maxsim_kernel: register-staged fp32->fp16 LDS GEMM (BK=64, double-buffered,
//   XOR-swizzled), norms computed on the fly from the same data (sum of
//   squares accumulated during staging), epilogue applies (1/|k|)*mask per
//   column, row-max, and folds 1/|q| into the partial maxes.
// logits_kernel + finalize: tiny reductions.

constexpr int NB = 128;
constexpr int LQ = 256;
constexpr int LK = 512;
constexpr int DD = 1024;

#define TEMP_INV 20.0f
#define EPSN 1e-12f

typedef __fp16 fp16x2 __attribute__((ext_vector_type(2)));   // cvt_pkrtz return
typedef _Float16 f16x8 __attribute__((ext_vector_type(8)));  // MFMA operand
typedef float f32x4 __attribute__((ext_vector_type(4)));

#define BM 128
#define BN 128
#define BK 64
#define KITERS (DD / BK)   // 16

__device__ inline f16x8 cvt8(float4 a, float4 b) {
  union { f16x8 v; fp16x2 h[4]; } u;
  u.h[0] = __builtin_amdgcn_cvt_pkrtz(a.x, a.y);
  u.h[1] = __builtin_amdgcn_cvt_pkrtz(a.z, a.w);
  u.h[2] = __builtin_amdgcn_cvt_pkrtz(b.x, b.y);
  u.h[3] = __builtin_amdgcn_cvt_pkrtz(b.z, b.w);
  return u.v;
}

__global__ __launch_bounds__(256) void maxsim_kernel(
    const float* __restrict__ q, const float* __restrict__ pk,
    const float* __restrict__ nk, const int* __restrict__ pmask,
    const int* __restrict__ nmask, float* __restrict__ part) {
  // 64 KB total: two fp16 double-buffered tiles; epilogue aux aliased on As[0]
  __shared__ _Float16 __align__(16) As[2][BM * BK];  // 32 KB
  __shared__ _Float16 __align__(16) Bs[2][BN * BK];  // 32 KB

  const int x = blockIdx.x;
  const int b = blockIdx.y;
  const int mt = x >> 3;         // 0..1  (q tile)
  const int nt = (x >> 1) & 3;   // 0..3  (key tile)
  const int kt = x & 1;          // 0=pos 1=neg

  const float* kbase = kt ? nk : pk;
  const int* mbase = kt ? nmask : pmask;

  const float* Ag = q + ((size_t)b * LQ + mt * BM) * DD;
  const float* Bg = kbase + ((size_t)b * LK + nt * BN) * DD;

  const int tid = threadIdx.x;
  const int lane = tid & 63;
  const int w = tid >> 6;
  const int wr = w >> 1, wc = w & 1;
  const int frow = lane & 15;
  const int kgrp = lane >> 4;    // 0..3

  // staging map: thread t -> rows (t>>3)+32i (i=0..3), 16B-chunk c = t&7
  const int srow0 = tid >> 3;    // 0..31
  const int sc = tid & 7;        // chunk of 8 cols

  const float* pa[4];
  const float* pb[4];
  #pragma unroll
  for (int i = 0; i < 4; ++i) {
    pa[i] = Ag + (size_t)(srow0 + 32 * i) * DD + sc * 8;
    pb[i] = Bg + (size_t)(srow0 + 32 * i) * DD + sc * 8;
  }

  float ssqA[4] = {0.f, 0.f, 0.f, 0.f};
  float ssqB[4] = {0.f, 0.f, 0.f, 0.f};
  f32x4 acc[4][4] = {};

  auto LOADS = [&](int it, float4 (&ra)[4][2], float4 (&rb)[4][2]) {
    const int koff = it * BK;
    #pragma unroll
    for (int i = 0; i < 4; ++i) {
      ra[i][0] = *(const float4*)(pa[i] + koff);
      ra[i][1] = *(const float4*)(pa[i] + koff + 4);
      rb[i][0] = *(const float4*)(pb[i] + koff);
      rb[i][1] = *(const float4*)(pb[i] + koff + 4);
    }
  };
  auto STORE = [&](int bsel, float4 (&ra)[4][2], float4 (&rb)[4][2]) {
    #pragma unroll
    for (int i = 0; i < 4; ++i) {
      float4 a0 = ra[i][0], a1 = ra[i][1], b0 = rb[i][0], b1 = rb[i][1];
      ssqA[i] += a0.x * a0.x + a0.y * a0.y + a0.z * a0.z + a0.w * a0.w +
                 a1.x * a1.x + a1.y * a1.y + a1.z * a1.z + a1.w * a1.w;
      ssqB[i] += b0.x * b0.x + b0.y * b0.y + b0.z * b0.z + b0.w * b0.w +
                 b1.x * b1.x + b1.y * b1.y + b1.z * b1.z + b1.w * b1.w;
      const int row = srow0 + 32 * i;
      const int cofs = ((sc ^ (row & 7)) << 3);
      *(f16x8*)&As[bsel][row * BK + cofs] = cvt8(a0, a1);
      *(f16x8*)&Bs[bsel][row * BK + cofs] = cvt8(b0, b1);
    }
  };

  {
    float4 ca[4][2], cb[4][2];
    LOADS(0, ca, cb);
    STORE(0, ca, cb);
  }
  __syncthreads();

  int buf = 0;
  for (int it = 0; it < KITERS; ++it) {
    float4 na[4][2], nb[4][2];
    if (it < KITERS - 1) LOADS(it + 1, na, nb);  // issue early (T14)

    #pragma unroll
    for (int ks = 0; ks < 2; ++ks) {
      f16x8 af[4], bf[4];
      #pragma unroll
      for (int m = 0; m < 4; ++m) {
        const int row = wr * 64 + m * 16 + frow;
        const int ch = ks * 4 + kgrp;
        af[m] = *(const f16x8*)&As[buf][row * BK + ((ch ^ (row & 7)) << 3)];
      }
      #pragma unroll
      for (int n = 0; n < 4; ++n) {
        const int row = wc * 64 + n * 16 + frow;
        const int ch = ks * 4 + kgrp;
        bf[n] = *(const f16x8*)&Bs[buf][row * BK + ((ch ^ (row & 7)) << 3)];
      }
      #pragma unroll
      for (int m = 0; m < 4; ++m)
        #pragma unroll
        for (int n = 0; n < 4; ++n)
          acc[m][n] = __builtin_amdgcn_mfma_f32_16x16x32_f16(af[m], bf[n], acc[m][n], 0, 0, 0);
    }

    if (it < KITERS - 1) STORE(buf ^ 1, na, nb);
    __syncthreads();
    buf ^= 1;
  }

  // ---- epilogue: norms, column scales, row-max ----
  // reduce ssq over the 8 chunk-lanes sharing each row (8-aligned lane groups)
  #pragma unroll
  for (int off = 1; off < 8; off <<= 1) {
    #pragma unroll
    for (int i = 0; i < 4; ++i) {
      ssqA[i] += __shfl_xor(ssqA[i], off);
      ssqB[i] += __shfl_xor(ssqB[i], off);
    }
  }

  // aux arrays aliased onto As[0] (all As/Bs reads are done; barrier above)
  float* const aux = reinterpret_cast<float*>(&As[0][0]);
  float* const cs = aux;            // [BN]  (1/|k|)*mask
  float* const invA_s = aux + BN;   // [BM]  1/|q|
  float* const rmax = aux + BN + BM;  // [BM][2]

  if (sc == 0) {
    #pragma unroll
    for (int i = 0; i < 4; ++i) {
      const int row = srow0 + 32 * i;
      invA_s[row] = 1.0f / fmaxf(sqrtf(ssqA[i]), EPSN);
      const int key = nt * BN + row;
      const float mk = mbase[(size_t)b * LK + key] ? 1.0f : 0.0f;
      cs[row] = mk / fmaxf(sqrtf(ssqB[i]), EPSN);
    }
  }
  __syncthreads();

  float vmax[4][4];
  #pragma unroll
  for (int m = 0; m < 4; ++m)
    #pragma unroll
    for (int r = 0; r < 4; ++r) vmax[m][r] = -INFINITY;
  #pragma unroll
  for (int n = 0; n < 4; ++n) {
    const float s = cs[wc * 64 + n * 16 + frow];
    #pragma unroll
    for (int m = 0; m < 4; ++m)
      #pragma unroll
      for (int r = 0; r < 4; ++r)
        vmax[m][r] = fmaxf(vmax[m][r], acc[m][n][r] * s);
  }
  #pragma unroll
  for (int off = 1; off < 16; off <<= 1)
    #pragma unroll
    for (int m = 0; m < 4; ++m)
      #pragma unroll
      for (int r = 0; r < 4; ++r)
        vmax[m][r] = fmaxf(vmax[m][r], __shfl_xor(vmax[m][r], off));
  if ((lane & 15) == 0) {
    #pragma unroll
    for (int m = 0; m < 4; ++m)
      #pragma unroll
      for (int r = 0; r < 4; ++r)
        rmax[(wr * 64 + m * 16 + kgrp * 4 + r) * 2 + wc] = vmax[m][r];
  }
  __syncthreads();
  if (tid < BM) {
    const float v = fmaxf(rmax[tid * 2], rmax[tid * 2 + 1]) * invA_s[tid];
    part[(((size_t)kt * NB + b) * 4 + nt) * LQ + mt * BM + tid] = v;
  }
}

// ---------------- logits + softplus per batch ----------------
__global__ __launch_bounds__(256) void logits_kernel(
    const float* __restrict__ part, const int* __restrict__ qmask,
    float* __restrict__ nll) {
  int b = blockIdx.x;
  int t = threadIdx.x;  // = lq
  float mp = -INFINITY, mn = -INFINITY;
  #pragma unroll
  for (int ntile = 0; ntile < 4; ++ntile) {
    mp = fmaxf(mp, part[(((size_t)0 * NB + b) * 4 + ntile) * LQ + t]);
    mn = fmaxf(mn, part[(((size_t)1 * NB + b) * 4 + ntile) * LQ + t]);
  }
  float qm = qmask[(size_t)b * LQ + t] ? 1.0f : 0.0f;
  float p = mp * qm;  // 1/|q| already folded into part
  float n = mn * qm;
  #pragma unroll
  for (int o = 32; o; o >>= 1) { p += __shfl_down(p, o); n += __shfl_down(n, o); }
  __shared__ float sp[4], sn[4];
  int lane = t & 63, w = t >> 6;
  if (lane == 0) { sp[w] = p; sn[w] = n; }
  __syncthreads();
  if (t == 0) {
    float ps = sp[0] + sp[1] + sp[2] + sp[3];
    float ns = sn[0] + sn[1] + sn[2] + sn[3];
    float z = (ns - ps) * TEMP_INV;
    nll[b] = z > 0.0f ? z + log1pf(expf(-z)) : log1pf(expf(z));
  }
}

__global__ void finalize_kernel(const float* __restrict__ nll, float* __restrict__ out) {
  __shared__ float s[128];
  int t = threadIdx.x;
  s[t] = nll[t];
  __syncthreads();
  #pragma unroll
  for (int o = 64; o; o >>= 1) {
    if (t < o) s[t] += s[t + o];
    __syncthreads();
  }
  if (t == 0) out[0] = s[0] * (1.0f / 128.0f);
}

extern "C" void kernel_launch(void* const* d_in, const int* in_sizes, int n_in,
                              void* d_out, int out_size, void* d_ws, size_t ws_size,
                              hipStream_t stream) {
  const float* q = (const float*)d_in[0];
  const float* pk = (const float*)d_in[1];
  const float* nk = (const float*)d_in[2];
  const int* qm = (const int*)d_in[3];
  const int* pm = (const int*)d_in[4];
  const int* nm = (const int*)d_in[5];

  float* ws = (float*)d_ws;
  float* part = ws;                // 262144 floats: [kt][b][nt][lq]
  float* nll = part + 262144;      // 128 floats

  maxsim_kernel<<<dim3(16, NB, 1), 256, 0, stream>>>(q, pk, nk, pm, nm, part);
  logits_kernel<<<NB, 256, 0, stream>>>(part, qm, nll);
  finalize_kernel<<<1, 128, 0, stream>>>(nll, (float*)d_out);
}

// Round 4
// 248.756 us; speedup vs baseline: 1.3968x; 1.1043x over previous
//
#include <hip/hip_runtime.h>
#include <hip/hip_fp16.h>
#include <math.h>

// MaxSim contrastive loss, MI355X — fused single-pass version.
// maxsim_kernel: register-staged fp32->fp16 LDS GEMM (BK=64, double-buffered,
//   XOR-swizzled), norms computed on the fly during staging, epilogue applies
//   (1/|k|)*mask per column, row-max, folds 1/|q| into partials.
// __launch_bounds__(256,2): LDS (64KB) caps us at 2 blocks/CU anyway, so give
//   the register allocator the full 256-VGPR budget — keeps the 16 staging
//   loads in flight across the MFMA block (round-3 failure: 104 VGPRs sank
//   the loads next to the ds_writes, serializing HBM latency).

constexpr int NB = 128;
constexpr int LQ = 256;
constexpr int LK = 512;
constexpr int DD = 1024;

#define TEMP_INV 20.0f
#define EPSN 1e-12f

typedef __fp16 fp16x2 __attribute__((ext_vector_type(2)));   // cvt_pkrtz return
typedef _Float16 f16x8 __attribute__((ext_vector_type(8)));  // MFMA operand
typedef float f32x4 __attribute__((ext_vector_type(4)));

#define BM 128
#define BN 128
#define BK 64
#define KITERS (DD / BK)   // 16

__device__ inline f16x8 cvt8(float4 a, float4 b) {
  union { f16x8 v; fp16x2 h[4]; } u;
  u.h[0] = __builtin_amdgcn_cvt_pkrtz(a.x, a.y);
  u.h[1] = __builtin_amdgcn_cvt_pkrtz(a.z, a.w);
  u.h[2] = __builtin_amdgcn_cvt_pkrtz(b.x, b.y);
  u.h[3] = __builtin_amdgcn_cvt_pkrtz(b.z, b.w);
  return u.v;
}

__global__ __launch_bounds__(256, 2) void maxsim_kernel(
    const float* __restrict__ q, const float* __restrict__ pk,
    const float* __restrict__ nk, const int* __restrict__ pmask,
    const int* __restrict__ nmask, float* __restrict__ part) {
  __shared__ _Float16 __align__(16) As[2][BM * BK];  // 32 KB
  __shared__ _Float16 __align__(16) Bs[2][BN * BK];  // 32 KB

  const int x = blockIdx.x;
  const int b = blockIdx.y;
  const int mt = x >> 3;         // 0..1  (q tile)
  const int nt = (x >> 1) & 3;   // 0..3  (key tile)
  const int kt = x & 1;          // 0=pos 1=neg

  const float* kbase = kt ? nk : pk;
  const int* mbase = kt ? nmask : pmask;

  const float* Ag = q + ((size_t)b * LQ + mt * BM) * DD;
  const float* Bg = kbase + ((size_t)b * LK + nt * BN) * DD;

  const int tid = threadIdx.x;
  const int lane = tid & 63;
  const int w = tid >> 6;
  const int wr = w >> 1, wc = w & 1;
  const int frow = lane & 15;
  const int kgrp = lane >> 4;    // 0..3

  // staging map: thread t -> rows (t>>3)+32i (i=0..3), 16B-chunk c = t&7
  const int srow0 = tid >> 3;    // 0..31
  const int sc = tid & 7;        // chunk of 8 cols

  const float* pa[4];
  const float* pb[4];
  #pragma unroll
  for (int i = 0; i < 4; ++i) {
    pa[i] = Ag + (size_t)(srow0 + 32 * i) * DD + sc * 8;
    pb[i] = Bg + (size_t)(srow0 + 32 * i) * DD + sc * 8;
  }

  float ssqA[4] = {0.f, 0.f, 0.f, 0.f};
  float ssqB[4] = {0.f, 0.f, 0.f, 0.f};
  f32x4 acc[4][4] = {};

  auto LOADS = [&](int it, float4 (&ra)[4][2], float4 (&rb)[4][2]) {
    const int koff = it * BK;
    #pragma unroll
    for (int i = 0; i < 4; ++i) {
      ra[i][0] = *(const float4*)(pa[i] + koff);
      ra[i][1] = *(const float4*)(pa[i] + koff + 4);
      rb[i][0] = *(const float4*)(pb[i] + koff);
      rb[i][1] = *(const float4*)(pb[i] + koff + 4);
    }
  };
  auto STORE = [&](int bsel, float4 (&ra)[4][2], float4 (&rb)[4][2]) {
    #pragma unroll
    for (int i = 0; i < 4; ++i) {
      float4 a0 = ra[i][0], a1 = ra[i][1], b0 = rb[i][0], b1 = rb[i][1];
      ssqA[i] += a0.x * a0.x + a0.y * a0.y + a0.z * a0.z + a0.w * a0.w +
                 a1.x * a1.x + a1.y * a1.y + a1.z * a1.z + a1.w * a1.w;
      ssqB[i] += b0.x * b0.x + b0.y * b0.y + b0.z * b0.z + b0.w * b0.w +
                 b1.x * b1.x + b1.y * b1.y + b1.z * b1.z + b1.w * b1.w;
      const int row = srow0 + 32 * i;
      const int cofs = ((sc ^ (row & 7)) << 3);
      *(f16x8*)&As[bsel][row * BK + cofs] = cvt8(a0, a1);
      *(f16x8*)&Bs[bsel][row * BK + cofs] = cvt8(b0, b1);
    }
  };
  auto COMPUTE = [&](int bsel) {
    #pragma unroll
    for (int ks = 0; ks < 2; ++ks) {
      f16x8 af[4], bf[4];
      #pragma unroll
      for (int m = 0; m < 4; ++m) {
        const int row = wr * 64 + m * 16 + frow;
        const int ch = ks * 4 + kgrp;
        af[m] = *(const f16x8*)&As[bsel][row * BK + ((ch ^ (row & 7)) << 3)];
      }
      #pragma unroll
      for (int n = 0; n < 4; ++n) {
        const int row = wc * 64 + n * 16 + frow;
        const int ch = ks * 4 + kgrp;
        bf[n] = *(const f16x8*)&Bs[bsel][row * BK + ((ch ^ (row & 7)) << 3)];
      }
      #pragma unroll
      for (int m = 0; m < 4; ++m)
        #pragma unroll
        for (int n = 0; n < 4; ++n)
          acc[m][n] = __builtin_amdgcn_mfma_f32_16x16x32_f16(af[m], bf[n], acc[m][n], 0, 0, 0);
    }
  };

  {
    float4 ca[4][2], cb[4][2];
    LOADS(0, ca, cb);
    STORE(0, ca, cb);
  }
  __syncthreads();

  int buf = 0;
  for (int it = 0; it < KITERS - 1; ++it) {
    float4 na[4][2], nb[4][2];
    LOADS(it + 1, na, nb);   // issue early — hides HBM latency under MFMAs
    COMPUTE(buf);
    STORE(buf ^ 1, na, nb);
    __syncthreads();
    buf ^= 1;
  }
  COMPUTE(buf);              // final K-tile (buf == 1)

  // ---- epilogue: norms, column scales, row-max ----
  #pragma unroll
  for (int off = 1; off < 8; off <<= 1) {
    #pragma unroll
    for (int i = 0; i < 4; ++i) {
      ssqA[i] += __shfl_xor(ssqA[i], off);
      ssqB[i] += __shfl_xor(ssqB[i], off);
    }
  }

  // aux arrays aliased onto As[0]; final COMPUTE read As[1]/Bs[1] so no
  // conflict with in-flight reads; barrier below orders write->read.
  float* const aux = reinterpret_cast<float*>(&As[0][0]);
  float* const cs = aux;              // [BN]  (1/|k|)*mask
  float* const invA_s = aux + BN;     // [BM]  1/|q|
  float* const rmax = aux + BN + BM;  // [BM][2]

  if (sc == 0) {
    #pragma unroll
    for (int i = 0; i < 4; ++i) {
      const int row = srow0 + 32 * i;
      invA_s[row] = 1.0f / fmaxf(sqrtf(ssqA[i]), EPSN);
      const int key = nt * BN + row;
      const float mk = mbase[(size_t)b * LK + key] ? 1.0f : 0.0f;
      cs[row] = mk / fmaxf(sqrtf(ssqB[i]), EPSN);
    }
  }
  __syncthreads();

  float vmax[4][4];
  #pragma unroll
  for (int m = 0; m < 4; ++m)
    #pragma unroll
    for (int r = 0; r < 4; ++r) vmax[m][r] = -INFINITY;
  #pragma unroll
  for (int n = 0; n < 4; ++n) {
    const float s = cs[wc * 64 + n * 16 + frow];
    #pragma unroll
    for (int m = 0; m < 4; ++m)
      #pragma unroll
      for (int r = 0; r < 4; ++r)
        vmax[m][r] = fmaxf(vmax[m][r], acc[m][n][r] * s);
  }
  #pragma unroll
  for (int off = 1; off < 16; off <<= 1)
    #pragma unroll
    for (int m = 0; m < 4; ++m)
      #pragma unroll
      for (int r = 0; r < 4; ++r)
        vmax[m][r] = fmaxf(vmax[m][r], __shfl_xor(vmax[m][r], off));
  if ((lane & 15) == 0) {
    #pragma unroll
    for (int m = 0; m < 4; ++m)
      #pragma unroll
      for (int r = 0; r < 4; ++r)
        rmax[(wr * 64 + m * 16 + kgrp * 4 + r) * 2 + wc] = vmax[m][r];
  }
  __syncthreads();
  if (tid < BM) {
    const float v = fmaxf(rmax[tid * 2], rmax[tid * 2 + 1]) * invA_s[tid];
    part[(((size_t)kt * NB + b) * 4 + nt) * LQ + mt * BM + tid] = v;
  }
}

// ---------------- logits + softplus per batch ----------------
__global__ __launch_bounds__(256) void logits_kernel(
    const float* __restrict__ part, const int* __restrict__ qmask,
    float* __restrict__ nll) {
  int b = blockIdx.x;
  int t = threadIdx.x;  // = lq
  float mp = -INFINITY, mn = -INFINITY;
  #pragma unroll
  for (int ntile = 0; ntile < 4; ++ntile) {
    mp = fmaxf(mp, part[(((size_t)0 * NB + b) * 4 + ntile) * LQ + t]);
    mn = fmaxf(mn, part[(((size_t)1 * NB + b) * 4 + ntile) * LQ + t]);
  }
  float qm = qmask[(size_t)b * LQ + t] ? 1.0f : 0.0f;
  float p = mp * qm;  // 1/|q| already folded into part
  float n = mn * qm;
  #pragma unroll
  for (int o = 32; o; o >>= 1) { p += __shfl_down(p, o); n += __shfl_down(n, o); }
  __shared__ float sp[4], sn[4];
  int lane = t & 63, w = t >> 6;
  if (lane == 0) { sp[w] = p; sn[w] = n; }
  __syncthreads();
  if (t == 0) {
    float ps = sp[0] + sp[1] + sp[2] + sp[3];
    float ns = sn[0] + sn[1] + sn[2] + sn[3];
    float z = (ns - ps) * TEMP_INV;
    nll[b] = z > 0.0f ? z + log1pf(expf(-z)) : log1pf(expf(z));
  }
}

__global__ void finalize_kernel(const float* __restrict__ nll, float* __restrict__ out) {
  __shared__ float s[128];
  int t = threadIdx.x;
  s[t] = nll[t];
  __syncthreads();
  #pragma unroll
  for (int o = 64; o; o >>= 1) {
    if (t < o) s[t] += s[t + o];
    __syncthreads();
  }
  if (t == 0) out[0] = s[0] * (1.0f / 128.0f);
}

extern "C" void kernel_launch(void* const* d_in, const int* in_sizes, int n_in,
                              void* d_out, int out_size, void* d_ws, size_t ws_size,
                              hipStream_t stream) {
  const float* q = (const float*)d_in[0];
  const float* pk = (const float*)d_in[1];
  const float* nk = (const float*)d_in[2];
  const int* qm = (const int*)d_in[3];
  const int* pm = (const int*)d_in[4];
  const int* nm = (const int*)d_in[5];

  float* ws = (float*)d_ws;
  float* part = ws;                // 262144 floats: [kt][b][nt][lq]
  float* nll = part + 262144;      // 128 floats

  maxsim_kernel<<<dim3(16, NB, 1), 256, 0, stream>>>(q, pk, nk, pm, nm, part);
  logits_kernel<<<NB, 256, 0, stream>>>(part, qm, nll);
  finalize_kernel<<<1, 128, 0, stream>>>(nll, (float*)d_out);
}

// Round 5
// 244.294 us; speedup vs baseline: 1.4223x; 1.0183x over previous
//
#include <hip/hip_runtime.h>
#include <hip/hip_fp16.h>
#include <math.h>

// MaxSim contrastive loss, MI355X — fused single-pass version.
// maxsim_kernel: register-staged fp32->fp16 LDS GEMM (BK=64, double-buffered,
//   XOR-swizzled), norms computed on the fly during staging, epilogue applies
//   (1/|k|)*mask per column, row-max, folds 1/|q| into partials.
// Round-5 change: __builtin_amdgcn_sched_barrier(0) between LOADS and COMPUTE.
//   Round 3/4 failure: the scheduler sank the 16 staging loads down next to
//   STORE (VGPR_Count ~100 proved it), exposing full HBM latency every K-iter.
//   The fence pins the loads above the MFMA block so they stay in flight
//   during COMPUTE (T14 issue-early / write-late, enforced at schedule level).

constexpr int NB = 128;
constexpr int LQ = 256;
constexpr int LK = 512;
constexpr int DD = 1024;

#define TEMP_INV 20.0f
#define EPSN 1e-12f

typedef __fp16 fp16x2 __attribute__((ext_vector_type(2)));   // cvt_pkrtz return
typedef _Float16 f16x8 __attribute__((ext_vector_type(8)));  // MFMA operand
typedef float f32x4 __attribute__((ext_vector_type(4)));

#define BM 128
#define BN 128
#define BK 64
#define KITERS (DD / BK)   // 16

__device__ inline f16x8 cvt8(float4 a, float4 b) {
  union { f16x8 v; fp16x2 h[4]; } u;
  u.h[0] = __builtin_amdgcn_cvt_pkrtz(a.x, a.y);
  u.h[1] = __builtin_amdgcn_cvt_pkrtz(a.z, a.w);
  u.h[2] = __builtin_amdgcn_cvt_pkrtz(b.x, b.y);
  u.h[3] = __builtin_amdgcn_cvt_pkrtz(b.z, b.w);
  return u.v;
}

__global__ __launch_bounds__(256, 2) void maxsim_kernel(
    const float* __restrict__ q, const float* __restrict__ pk,
    const float* __restrict__ nk, const int* __restrict__ pmask,
    const int* __restrict__ nmask, float* __restrict__ part) {
  __shared__ _Float16 __align__(16) As[2][BM * BK];  // 32 KB
  __shared__ _Float16 __align__(16) Bs[2][BN * BK];  // 32 KB

  const int x = blockIdx.x;
  const int b = blockIdx.y;
  const int mt = x >> 3;         // 0..1  (q tile)
  const int nt = (x >> 1) & 3;   // 0..3  (key tile)
  const int kt = x & 1;          // 0=pos 1=neg

  const float* kbase = kt ? nk : pk;
  const int* mbase = kt ? nmask : pmask;

  const float* Ag = q + ((size_t)b * LQ + mt * BM) * DD;
  const float* Bg = kbase + ((size_t)b * LK + nt * BN) * DD;

  const int tid = threadIdx.x;
  const int lane = tid & 63;
  const int w = tid >> 6;
  const int wr = w >> 1, wc = w & 1;
  const int frow = lane & 15;
  const int kgrp = lane >> 4;    // 0..3

  // staging map: thread t -> rows (t>>3)+32i (i=0..3), 16B-chunk c = t&7
  const int srow0 = tid >> 3;    // 0..31
  const int sc = tid & 7;        // chunk of 8 cols

  const float* pa[4];
  const float* pb[4];
  #pragma unroll
  for (int i = 0; i < 4; ++i) {
    pa[i] = Ag + (size_t)(srow0 + 32 * i) * DD + sc * 8;
    pb[i] = Bg + (size_t)(srow0 + 32 * i) * DD + sc * 8;
  }

  float ssqA[4] = {0.f, 0.f, 0.f, 0.f};
  float ssqB[4] = {0.f, 0.f, 0.f, 0.f};
  f32x4 acc[4][4] = {};

  auto LOADS = [&](int it, float4 (&ra)[4][2], float4 (&rb)[4][2]) {
    const int koff = it * BK;
    #pragma unroll
    for (int i = 0; i < 4; ++i) {
      ra[i][0] = *(const float4*)(pa[i] + koff);
      ra[i][1] = *(const float4*)(pa[i] + koff + 4);
      rb[i][0] = *(const float4*)(pb[i] + koff);
      rb[i][1] = *(const float4*)(pb[i] + koff + 4);
    }
  };
  auto STORE = [&](int bsel, float4 (&ra)[4][2], float4 (&rb)[4][2]) {
    #pragma unroll
    for (int i = 0; i < 4; ++i) {
      float4 a0 = ra[i][0], a1 = ra[i][1], b0 = rb[i][0], b1 = rb[i][1];
      ssqA[i] += a0.x * a0.x + a0.y * a0.y + a0.z * a0.z + a0.w * a0.w +
                 a1.x * a1.x + a1.y * a1.y + a1.z * a1.z + a1.w * a1.w;
      ssqB[i] += b0.x * b0.x + b0.y * b0.y + b0.z * b0.z + b0.w * b0.w +
                 b1.x * b1.x + b1.y * b1.y + b1.z * b1.z + b1.w * b1.w;
      const int row = srow0 + 32 * i;
      const int cofs = ((sc ^ (row & 7)) << 3);
      *(f16x8*)&As[bsel][row * BK + cofs] = cvt8(a0, a1);
      *(f16x8*)&Bs[bsel][row * BK + cofs] = cvt8(b0, b1);
    }
  };
  auto COMPUTE = [&](int bsel) {
    #pragma unroll
    for (int ks = 0; ks < 2; ++ks) {
      f16x8 af[4], bf[4];
      #pragma unroll
      for (int m = 0; m < 4; ++m) {
        const int row = wr * 64 + m * 16 + frow;
        const int ch = ks * 4 + kgrp;
        af[m] = *(const f16x8*)&As[bsel][row * BK + ((ch ^ (row & 7)) << 3)];
      }
      #pragma unroll
      for (int n = 0; n < 4; ++n) {
        const int row = wc * 64 + n * 16 + frow;
        const int ch = ks * 4 + kgrp;
        bf[n] = *(const f16x8*)&Bs[bsel][row * BK + ((ch ^ (row & 7)) << 3)];
      }
      #pragma unroll
      for (int m = 0; m < 4; ++m)
        #pragma unroll
        for (int n = 0; n < 4; ++n)
          acc[m][n] = __builtin_amdgcn_mfma_f32_16x16x32_f16(af[m], bf[n], acc[m][n], 0, 0, 0);
    }
  };

  {
    float4 ca[4][2], cb[4][2];
    LOADS(0, ca, cb);
    STORE(0, ca, cb);
  }
  __syncthreads();

  int buf = 0;
  for (int it = 0; it < KITERS - 1; ++it) {
    float4 na[4][2], nb[4][2];
    LOADS(it + 1, na, nb);   // issue early — must stay above the fence
    // Hard scheduling fence: the 16 global loads above may NOT sink below
    // this point (the round-3/4 regression). Their vmcnt-wait lands at the
    // first use inside STORE, so HBM latency hides under COMPUTE's MFMAs.
    __builtin_amdgcn_sched_barrier(0);
    COMPUTE(buf);
    STORE(buf ^ 1, na, nb);
    __syncthreads();
    buf ^= 1;
  }
  COMPUTE(buf);              // final K-tile (buf == 1)

  // ---- epilogue: norms, column scales, row-max ----
  #pragma unroll
  for (int off = 1; off < 8; off <<= 1) {
    #pragma unroll
    for (int i = 0; i < 4; ++i) {
      ssqA[i] += __shfl_xor(ssqA[i], off);
      ssqB[i] += __shfl_xor(ssqB[i], off);
    }
  }

  // aux arrays aliased onto As[0]; final COMPUTE read As[1]/Bs[1] so no
  // conflict with in-flight reads; barrier below orders write->read.
  float* const aux = reinterpret_cast<float*>(&As[0][0]);
  float* const cs = aux;              // [BN]  (1/|k|)*mask
  float* const invA_s = aux + BN;     // [BM]  1/|q|
  float* const rmax = aux + BN + BM;  // [BM][2]

  if (sc == 0) {
    #pragma unroll
    for (int i = 0; i < 4; ++i) {
      const int row = srow0 + 32 * i;
      invA_s[row] = 1.0f / fmaxf(sqrtf(ssqA[i]), EPSN);
      const int key = nt * BN + row;
      const float mk = mbase[(size_t)b * LK + key] ? 1.0f : 0.0f;
      cs[row] = mk / fmaxf(sqrtf(ssqB[i]), EPSN);
    }
  }
  __syncthreads();

  float vmax[4][4];
  #pragma unroll
  for (int m = 0; m < 4; ++m)
    #pragma unroll
    for (int r = 0; r < 4; ++r) vmax[m][r] = -INFINITY;
  #pragma unroll
  for (int n = 0; n < 4; ++n) {
    const float s = cs[wc * 64 + n * 16 + frow];
    #pragma unroll
    for (int m = 0; m < 4; ++m)
      #pragma unroll
      for (int r = 0; r < 4; ++r)
        vmax[m][r] = fmaxf(vmax[m][r], acc[m][n][r] * s);
  }
  #pragma unroll
  for (int off = 1; off < 16; off <<= 1)
    #pragma unroll
    for (int m = 0; m < 4; ++m)
      #pragma unroll
      for (int r = 0; r < 4; ++r)
        vmax[m][r] = fmaxf(vmax[m][r], __shfl_xor(vmax[m][r], off));
  if ((lane & 15) == 0) {
    #pragma unroll
    for (int m = 0; m < 4; ++m)
      #pragma unroll
      for (int r = 0; r < 4; ++r)
        rmax[(wr * 64 + m * 16 + kgrp * 4 + r) * 2 + wc] = vmax[m][r];
  }
  __syncthreads();
  if (tid < BM) {
    const float v = fmaxf(rmax[tid * 2], rmax[tid * 2 + 1]) * invA_s[tid];
    part[(((size_t)kt * NB + b) * 4 + nt) * LQ + mt * BM + tid] = v;
  }
}

// ---------------- logits + softplus per batch ----------------
__global__ __launch_bounds__(256) void logits_kernel(
    const float* __restrict__ part, const int* __restrict__ qmask,
    float* __restrict__ nll) {
  int b = blockIdx.x;
  int t = threadIdx.x;  // = lq
  float mp = -INFINITY, mn = -INFINITY;
  #pragma unroll
  for (int ntile = 0; ntile < 4; ++ntile) {
    mp = fmaxf(mp, part[(((size_t)0 * NB + b) * 4 + ntile) * LQ + t]);
    mn = fmaxf(mn, part[(((size_t)1 * NB + b) * 4 + ntile) * LQ + t]);
  }
  float qm = qmask[(size_t)b * LQ + t] ? 1.0f : 0.0f;
  float p = mp * qm;  // 1/|q| already folded into part
  float n = mn * qm;
  #pragma unroll
  for (int o = 32; o; o >>= 1) { p += __shfl_down(p, o); n += __shfl_down(n, o); }
  __shared__ float sp[4], sn[4];
  int lane = t & 63, w = t >> 6;
  if (lane == 0) { sp[w] = p; sn[w] = n; }
  __syncthreads();
  if (t == 0) {
    float ps = sp[0] + sp[1] + sp[2] + sp[3];
    float ns = sn[0] + sn[1] + sn[2] + sn[3];
    float z = (ns - ps) * TEMP_INV;
    nll[b] = z > 0.0f ? z + log1pf(expf(-z)) : log1pf(expf(z));
  }
}

__global__ void finalize_kernel(const float* __restrict__ nll, float* __restrict__ out) {
  __shared__ float s[128];
  int t = threadIdx.x;
  s[t] = nll[t];
  __syncthreads();
  #pragma unroll
  for (int o = 64; o; o >>= 1) {
    if (t < o) s[t] += s[t + o];
    __syncthreads();
  }
  if (t == 0) out[0] = s[0] * (1.0f / 128.0f);
}

extern "C" void kernel_launch(void* const* d_in, const int* in_sizes, int n_in,
                              void* d_out, int out_size, void* d_ws, size_t ws_size,
                              hipStream_t stream) {
  const float* q = (const float*)d_in[0];
  const float* pk = (const float*)d_in[1];
  const float* nk = (const float*)d_in[2];
  const int* qm = (const int*)d_in[3];
  const int* pm = (const int*)d_in[4];
  const int* nm = (const int*)d_in[5];

  float* ws = (float*)d_ws;
  float* part = ws;                // 262144 floats: [kt][b][nt][lq]
  float* nll = part + 262144;      // 128 floats

  maxsim_kernel<<<dim3(16, NB, 1), 256, 0, stream>>>(q, pk, nk, pm, nm, part);
  logits_kernel<<<NB, 256, 0, stream>>>(part, qm, nll);
  finalize_kernel<<<1, 128, 0, stream>>>(nll, (float*)d_out);
}

// Round 6
// 228.947 us; speedup vs baseline: 1.5177x; 1.0670x over previous
//
#include <hip/hip_runtime.h>
#include <hip/hip_fp16.h>
#include <math.h>

// MaxSim contrastive loss, MI355X — fused single-pass version.
// maxsim_kernel: register-staged fp32->fp16 LDS GEMM (BK=64, double-buffered,
//   XOR-swizzled), norms computed on the fly during staging, epilogue applies
//   (1/|k|)*mask per column, row-max, folds 1/|q| into partials.
// Round-6 change: 512 threads / 8 waves (4x2 wave grid) instead of 256/4.
//   Rounds 3-5 were latency-bound: 2 waves/SIMD can't hide ~900cy HBM latency
//   under ~160cy of MFMA issue. Same 64KB LDS -> still 2 blocks/CU, but now
//   4 waves/SIMD (2x TLP). Per-thread registers halve (staged 32 + acc 32),
//   fitting the 128-VGPR cap that 4 waves/SIMD requires.

constexpr int NB = 128;
constexpr int LQ = 256;
constexpr int LK = 512;
constexpr int DD = 1024;

#define TEMP_INV 20.0f
#define EPSN 1e-12f

typedef __fp16 fp16x2 __attribute__((ext_vector_type(2)));   // cvt_pkrtz return
typedef _Float16 f16x8 __attribute__((ext_vector_type(8)));  // MFMA operand
typedef float f32x4 __attribute__((ext_vector_type(4)));

#define BM 128
#define BN 128
#define BK 64
#define KITERS (DD / BK)   // 16

__device__ inline f16x8 cvt8(float4 a, float4 b) {
  union { f16x8 v; fp16x2 h[4]; } u;
  u.h[0] = __builtin_amdgcn_cvt_pkrtz(a.x, a.y);
  u.h[1] = __builtin_amdgcn_cvt_pkrtz(a.z, a.w);
  u.h[2] = __builtin_amdgcn_cvt_pkrtz(b.x, b.y);
  u.h[3] = __builtin_amdgcn_cvt_pkrtz(b.z, b.w);
  return u.v;
}

__global__ __launch_bounds__(512, 4) void maxsim_kernel(
    const float* __restrict__ q, const float* __restrict__ pk,
    const float* __restrict__ nk, const int* __restrict__ pmask,
    const int* __restrict__ nmask, float* __restrict__ part) {
  __shared__ _Float16 __align__(16) As[2][BM * BK];  // 32 KB
  __shared__ _Float16 __align__(16) Bs[2][BN * BK];  // 32 KB

  const int x = blockIdx.x;
  const int b = blockIdx.y;
  const int mt = x >> 3;         // 0..1  (q tile)
  const int nt = (x >> 1) & 3;   // 0..3  (key tile)
  const int kt = x & 1;          // 0=pos 1=neg

  const float* kbase = kt ? nk : pk;
  const int* mbase = kt ? nmask : pmask;

  const float* Ag = q + ((size_t)b * LQ + mt * BM) * DD;
  const float* Bg = kbase + ((size_t)b * LK + nt * BN) * DD;

  const int tid = threadIdx.x;
  const int lane = tid & 63;
  const int w = tid >> 6;        // 0..7
  const int wr = w >> 1;         // 0..3 : rows wr*32 + [0,32)
  const int wc = w & 1;          // 0..1 : cols wc*64 + [0,64)
  const int frow = lane & 15;
  const int kgrp = lane >> 4;    // 0..3

  // staging map: thread t -> rows (t>>3)+64i (i=0..1), 16B-chunk c = t&7
  const int srow0 = tid >> 3;    // 0..63
  const int sc = tid & 7;        // chunk of 8 cols

  const float* pa[2];
  const float* pb[2];
  #pragma unroll
  for (int i = 0; i < 2; ++i) {
    pa[i] = Ag + (size_t)(srow0 + 64 * i) * DD + sc * 8;
    pb[i] = Bg + (size_t)(srow0 + 64 * i) * DD + sc * 8;
  }

  float ssqA[2] = {0.f, 0.f};
  float ssqB[2] = {0.f, 0.f};
  f32x4 acc[2][4] = {};

  auto LOADS = [&](int it, float4 (&ra)[2][2], float4 (&rb)[2][2]) {
    const int koff = it * BK;
    #pragma unroll
    for (int i = 0; i < 2; ++i) {
      ra[i][0] = *(const float4*)(pa[i] + koff);
      ra[i][1] = *(const float4*)(pa[i] + koff + 4);
      rb[i][0] = *(const float4*)(pb[i] + koff);
      rb[i][1] = *(const float4*)(pb[i] + koff + 4);
    }
  };
  auto STORE = [&](int bsel, float4 (&ra)[2][2], float4 (&rb)[2][2]) {
    #pragma unroll
    for (int i = 0; i < 2; ++i) {
      float4 a0 = ra[i][0], a1 = ra[i][1], b0 = rb[i][0], b1 = rb[i][1];
      ssqA[i] += a0.x * a0.x + a0.y * a0.y + a0.z * a0.z + a0.w * a0.w +
                 a1.x * a1.x + a1.y * a1.y + a1.z * a1.z + a1.w * a1.w;
      ssqB[i] += b0.x * b0.x + b0.y * b0.y + b0.z * b0.z + b0.w * b0.w +
                 b1.x * b1.x + b1.y * b1.y + b1.z * b1.z + b1.w * b1.w;
      const int row = srow0 + 64 * i;
      const int cofs = ((sc ^ (row & 7)) << 3);
      *(f16x8*)&As[bsel][row * BK + cofs] = cvt8(a0, a1);
      *(f16x8*)&Bs[bsel][row * BK + cofs] = cvt8(b0, b1);
    }
  };
  auto COMPUTE = [&](int bsel) {
    #pragma unroll
    for (int ks = 0; ks < 2; ++ks) {
      const int ch = ks * 4 + kgrp;
      f16x8 af[2], bf[4];
      #pragma unroll
      for (int m = 0; m < 2; ++m) {
        const int row = wr * 32 + m * 16 + frow;
        af[m] = *(const f16x8*)&As[bsel][row * BK + ((ch ^ (row & 7)) << 3)];
      }
      #pragma unroll
      for (int n = 0; n < 4; ++n) {
        const int row = wc * 64 + n * 16 + frow;
        bf[n] = *(const f16x8*)&Bs[bsel][row * BK + ((ch ^ (row & 7)) << 3)];
      }
      #pragma unroll
      for (int m = 0; m < 2; ++m)
        #pragma unroll
        for (int n = 0; n < 4; ++n)
          acc[m][n] = __builtin_amdgcn_mfma_f32_16x16x32_f16(af[m], bf[n], acc[m][n], 0, 0, 0);
    }
  };

  {
    float4 ca[2][2], cb[2][2];
    LOADS(0, ca, cb);
    STORE(0, ca, cb);
  }
  __syncthreads();

  int buf = 0;
  for (int it = 0; it < KITERS - 1; ++it) {
    float4 na[2][2], nb[2][2];
    LOADS(it + 1, na, nb);   // issue early — must stay above the fence
    __builtin_amdgcn_sched_barrier(0);  // loads may not sink below this point
    COMPUTE(buf);
    STORE(buf ^ 1, na, nb);
    __syncthreads();
    buf ^= 1;
  }
  COMPUTE(buf);              // final K-tile (buf == 1)

  // ---- epilogue: norms, column scales, row-max ----
  #pragma unroll
  for (int off = 1; off < 8; off <<= 1) {
    #pragma unroll
    for (int i = 0; i < 2; ++i) {
      ssqA[i] += __shfl_xor(ssqA[i], off);
      ssqB[i] += __shfl_xor(ssqB[i], off);
    }
  }

  // aux arrays aliased onto As[0]; final COMPUTE read As[1]/Bs[1] so no
  // conflict with in-flight reads; barrier below orders write->read.
  float* const aux = reinterpret_cast<float*>(&As[0][0]);
  float* const cs = aux;              // [BN]  (1/|k|)*mask
  float* const invA_s = aux + BN;     // [BM]  1/|q|
  float* const rmax = aux + BN + BM;  // [BM][2]

  if (sc == 0) {
    #pragma unroll
    for (int i = 0; i < 2; ++i) {
      const int row = srow0 + 64 * i;
      invA_s[row] = 1.0f / fmaxf(sqrtf(ssqA[i]), EPSN);
      const int key = nt * BN + row;
      const float mk = mbase[(size_t)b * LK + key] ? 1.0f : 0.0f;
      cs[row] = mk / fmaxf(sqrtf(ssqB[i]), EPSN);
    }
  }
  __syncthreads();

  float vmax[2][4];
  #pragma unroll
  for (int m = 0; m < 2; ++m)
    #pragma unroll
    for (int r = 0; r < 4; ++r) vmax[m][r] = -INFINITY;
  #pragma unroll
  for (int n = 0; n < 4; ++n) {
    const float s = cs[wc * 64 + n * 16 + frow];
    #pragma unroll
    for (int m = 0; m < 2; ++m)
      #pragma unroll
      for (int r = 0; r < 4; ++r)
        vmax[m][r] = fmaxf(vmax[m][r], acc[m][n][r] * s);
  }
  #pragma unroll
  for (int off = 1; off < 16; off <<= 1)
    #pragma unroll
    for (int m = 0; m < 2; ++m)
      #pragma unroll
      for (int r = 0; r < 4; ++r)
        vmax[m][r] = fmaxf(vmax[m][r], __shfl_xor(vmax[m][r], off));
  if ((lane & 15) == 0) {
    #pragma unroll
    for (int m = 0; m < 2; ++m)
      #pragma unroll
      for (int r = 0; r < 4; ++r)
        rmax[(wr * 32 + m * 16 + kgrp * 4 + r) * 2 + wc] = vmax[m][r];
  }
  __syncthreads();
  if (tid < BM) {
    const float v = fmaxf(rmax[tid * 2], rmax[tid * 2 + 1]) * invA_s[tid];
    part[(((size_t)kt * NB + b) * 4 + nt) * LQ + mt * BM + tid] = v;
  }
}

// ---------------- logits + softplus per batch ----------------
__global__ __launch_bounds__(256) void logits_kernel(
    const float* __restrict__ part, const int* __restrict__ qmask,
    float* __restrict__ nll) {
  int b = blockIdx.x;
  int t = threadIdx.x;  // = lq
  float mp = -INFINITY, mn = -INFINITY;
  #pragma unroll
  for (int ntile = 0; ntile < 4; ++ntile) {
    mp = fmaxf(mp, part[(((size_t)0 * NB + b) * 4 + ntile) * LQ + t]);
    mn = fmaxf(mn, part[(((size_t)1 * NB + b) * 4 + ntile) * LQ + t]);
  }
  float qm = qmask[(size_t)b * LQ + t] ? 1.0f : 0.0f;
  float p = mp * qm;  // 1/|q| already folded into part
  float n = mn * qm;
  #pragma unroll
  for (int o = 32; o; o >>= 1) { p += __shfl_down(p, o); n += __shfl_down(n, o); }
  __shared__ float sp[4], sn[4];
  int lane = t & 63, w = t >> 6;
  if (lane == 0) { sp[w] = p; sn[w] = n; }
  __syncthreads();
  if (t == 0) {
    float ps = sp[0] + sp[1] + sp[2] + sp[3];
    float ns = sn[0] + sn[1] + sn[2] + sn[3];
    float z = (ns - ps) * TEMP_INV;
    nll[b] = z > 0.0f ? z + log1pf(expf(-z)) : log1pf(expf(z));
  }
}

__global__ void finalize_kernel(const float* __restrict__ nll, float* __restrict__ out) {
  __shared__ float s[128];
  int t = threadIdx.x;
  s[t] = nll[t];
  __syncthreads();
  #pragma unroll
  for (int o = 64; o; o >>= 1) {
    if (t < o) s[t] += s[t + o];
    __syncthreads();
  }
  if (t == 0) out[0] = s[0] * (1.0f / 128.0f);
}

extern "C" void kernel_launch(void* const* d_in, const int* in_sizes, int n_in,
                              void* d_out, int out_size, void* d_ws, size_t ws_size,
                              hipStream_t stream) {
  const float* q = (const float*)d_in[0];
  const float* pk = (const float*)d_in[1];
  const float* nk = (const float*)d_in[2];
  const int* qm = (const int*)d_in[3];
  const int* pm = (const int*)d_in[4];
  const int* nm = (const int*)d_in[5];

  float* ws = (float*)d_ws;
  float* part = ws;                // 262144 floats: [kt][b][nt][lq]
  float* nll = part + 262144;      // 128 floats

  maxsim_kernel<<<dim3(16, NB, 1), 512, 0, stream>>>(q, pk, nk, pm, nm, part);
  logits_kernel<<<NB, 256, 0, stream>>>(part, qm, nll);
  finalize_kernel<<<1, 128, 0, stream>>>(nll, (float*)d_out);
}